// Round 9
// baseline (2883.317 us; speedup 1.0000x reference)
//
#include <hip/hip_runtime.h>
#include <hip/hip_bf16.h>

typedef unsigned int uint;
typedef float v2f __attribute__((ext_vector_type(2)));

#define H_ 32
#define L_ 256
#define DK_ 32
#define DV_ 32
#define QAA 21
#define AQ_ 441      // 21*21
#define DREP 64
#define M_ 8192
#define LAMBDA_ 1e-3f

// fast-path J layout: per (r,j) block of JJSTR bytes; row a starts at a*JSTR.
// JSTR = 13 words (52 B): odd word stride -> 21 distinct start banks; sub-dword
// access measured conflict-free (r3/r5/r7: SQ_LDS_BANK_CONFLICT == 0).
#define JSTR 52
#define JJSTR 1104              // 21*52=1092, padded to 16B multiple
#define JCH 8                   // j's per staged chunk
#define CHUNK_B (JCH * JJSTR)   // 8832
#define NGRAN (CHUNK_B / 16)    // 552 16B granules
#define NCH (L_ / JCH)          // 32

// gather: block=512 threads, TM=2 m per thread -> 1024 m per block (mt=8, same
// staging traffic as the proven r7 layout), 24 waves/CU at (512,6).
#define TM 2
#define GBLK 512
// legacy-path params
#define JC 8
#define TML 4

// ---------------- softmax rows: P[h,i,j] = softmax_j(Q[h,i]·K[h,j]/sqrt(32)) ----------------
__global__ __launch_bounds__(256) void softmax_kernel(const float* __restrict__ Q,
                                                      const float* __restrict__ K,
                                                      float* __restrict__ P) {
  const int i = blockIdx.x, h = blockIdx.y, j = threadIdx.x;
  __shared__ float qrow[DK_];
  __shared__ float red[256];
  if (j < DK_) qrow[j] = Q[(h * L_ + i) * DK_ + j];
  __syncthreads();
  const float* krow = &K[(h * L_ + j) * DK_];
  float s = 0.f;
#pragma unroll
  for (int d = 0; d < DK_; ++d) s += qrow[d] * krow[d];
  s *= 0.17677669529663687f;  // 1/sqrt(32)
  red[j] = s;
  __syncthreads();
  for (int t = 128; t > 0; t >>= 1) {
    if (j < t) red[j] = fmaxf(red[j], red[j + t]);
    __syncthreads();
  }
  const float mx = red[0];
  __syncthreads();
  const float e = __expf(s - mx);
  red[j] = e;
  __syncthreads();
  for (int t = 128; t > 0; t >>= 1) {
    if (j < t) red[j] += red[j + t];
    __syncthreads();
  }
  P[(h * L_ + i) * L_ + j] = e / red[0];
}

// ---------------- A = 0.5*(P + P^T), LDS-tiled transpose ----------------
__global__ __launch_bounds__(256) void sym_kernel(const float* __restrict__ P,
                                                  float* __restrict__ A) {
  __shared__ float t1[32][33], t2[32][33];
  const int h = blockIdx.z;
  const int i0 = blockIdx.x * 32, j0 = blockIdx.y * 32;
  const int tx = threadIdx.x, ty = threadIdx.y;  // block (32,8)
#pragma unroll
  for (int ry = 0; ry < 4; ++ry) {
    const int row = ty + ry * 8;
    t1[row][tx] = P[(h * L_ + i0 + row) * L_ + j0 + tx];
    t2[row][tx] = P[(h * L_ + j0 + row) * L_ + i0 + tx];
  }
  __syncthreads();
#pragma unroll
  for (int ry = 0; ry < 4; ++ry) {
    const int row = ty + ry * 8;
    A[(h * L_ + i0 + row) * L_ + j0 + tx] = 0.5f * (t1[row][tx] + t2[tx][row]);
  }
}

// ---------------- Zs[j,m] = Z[j,m] * JSTR (u16 byte offsets) ----------------
__global__ __launch_bounds__(256) void zscale_kernel(const int* __restrict__ Z,
                                                     unsigned short* __restrict__ Zs) {
  const int i = (blockIdx.x * 256 + threadIdx.x) * 4;
  const int4 z = *(const int4*)(Z + i);
  ushort4 o;
  o.x = (unsigned short)(z.x * JSTR);
  o.y = (unsigned short)(z.y * JSTR);
  o.z = (unsigned short)(z.z * JSTR);
  o.w = (unsigned short)(z.w * JSTR);
  *(ushort4*)(Zs + i) = o;
}

// ---------------- Vaa[h,q,a] = exp(-gamma*max(D2,0)), V1 = reps @ Vm[h] ----------------
__global__ __launch_bounds__(256) void vaa_kernel(const float* __restrict__ reps,
                                                  const float* __restrict__ Vm,
                                                  float* __restrict__ Vaa) {
  const int h = blockIdx.x;
  __shared__ float V1[QAA * DV_];
  __shared__ float sq[QAA];
  for (int e = threadIdx.x; e < QAA * DV_; e += 256) {
    const int q = e >> 5, v = e & 31;
    float acc = 0.f;
#pragma unroll
    for (int d = 0; d < DREP; ++d) acc += reps[q * DREP + d] * Vm[(h * DREP + d) * DV_ + v];
    V1[e] = acc;
  }
  __syncthreads();
  if (threadIdx.x < QAA) {
    float acc = 0.f;
#pragma unroll
    for (int v = 0; v < DV_; ++v) { const float x = V1[threadIdx.x * DV_ + v]; acc += x * x; }
    sq[threadIdx.x] = acc;
  }
  __syncthreads();
  const float gamma = 1.f / 21.f;
  for (int e = threadIdx.x; e < AQ_; e += 256) {
    const int qq = e / QAA, aa = e - qq * QAA;
    float dot = 0.f;
#pragma unroll
    for (int v = 0; v < DV_; ++v) dot += V1[qq * DV_ + v] * V1[aa * DV_ + v];
    const float d2 = sq[qq] + sq[aa] - 2.f * dot;
    Vaa[h * AQ_ + e] = __expf(-gamma * fmaxf(d2, 0.f));
  }
}

// ---------------- reg = LAMBDA * sum_{h,h'} S[h,h'] * G[h,h'] ----------------
__global__ __launch_bounds__(256) void reg_kernel(const float* __restrict__ A,
                                                  const float* __restrict__ Vaa,
                                                  float* __restrict__ out) {
  const int h1 = blockIdx.x >> 5, h2 = blockIdx.x & 31;
  const float* A1 = A + h1 * (L_ * L_);
  const float* A2 = A + h2 * (L_ * L_);
  float s = 0.f;
  for (int idx = threadIdx.x; idx < L_ * L_; idx += 256) s += A1[idx] * A2[idx];
  s -= A1[threadIdx.x * (L_ + 1)] * A2[threadIdx.x * (L_ + 1)];
  float g = 0.f;
  const float* V1 = Vaa + h1 * AQ_;
  const float* V2 = Vaa + h2 * AQ_;
  for (int e = threadIdx.x; e < AQ_; e += 256) g += V1[e] * V2[e];
  __shared__ float redS[256], redG[256];
  redS[threadIdx.x] = s; redG[threadIdx.x] = g;
  __syncthreads();
  for (int t = 128; t > 0; t >>= 1) {
    if (threadIdx.x < t) {
      redS[threadIdx.x] += redS[threadIdx.x + t];
      redG[threadIdx.x] += redG[threadIdx.x + t];
    }
    __syncthreads();
  }
  if (threadIdx.x == 0) atomicAdd(out, LAMBDA_ * redS[0] * redG[0]);
}

static __device__ inline unsigned bf16_bits(float x) {
  __hip_bfloat16 b = __float2bfloat16(x);
  unsigned short u;
  __builtin_memcpy(&u, &b, 2);
  return (unsigned)u;
}

// ---------------- producer: J_g[r][j][a-row: 21 bf16 q-values, stride 52B] ----------------
// J[r,j,q,a] = sum_h A[h,r,j]*Vaa[h, a*21+q]  (Vaa symmetric); diag j==r zeroed.
__global__ __launch_bounds__(256) void jbuild_kernel(const float* __restrict__ A,
                                                     const float* __restrict__ Vaa,
                                                     unsigned char* __restrict__ Jg) {
  __shared__ float AT[L_ * H_];  // [j][h], 32 KB
  const int r = blockIdx.x, tid = threadIdx.x;
#pragma unroll
  for (int i = 0; i < H_; ++i) AT[tid * H_ + i] = A[(i * L_ + r) * L_ + tid];

  const int s = tid;
  const bool active = (s < 231);  // 21 rows * 11 words
  int a = 0, w = 0;
  if (active) { a = s / 11; w = s - a * 11; }
  const int q0 = 2 * w, q1 = q0 + 1;
  float vh0[H_], vh1[H_];
#pragma unroll
  for (int h = 0; h < H_; ++h) {
    vh0[h] = (active && q0 < QAA) ? Vaa[h * AQ_ + a * QAA + q0] : 0.f;
    vh1[h] = (active && q1 < QAA) ? Vaa[h * AQ_ + a * QAA + q1] : 0.f;
  }
  __syncthreads();

  unsigned char* dst = Jg + (size_t)r * (L_ * JJSTR);
  const int byte_off = a * JSTR + w * 4;
  for (int j = 0; j < L_; ++j) {
    float v0 = 0.f, v1 = 0.f;
    const float4* Ar4 = (const float4*)&AT[j * H_];
#pragma unroll
    for (int h4 = 0; h4 < H_ / 4; ++h4) {
      const float4 a4 = Ar4[h4];
      v0 += a4.x * vh0[h4 * 4 + 0]; v1 += a4.x * vh1[h4 * 4 + 0];
      v0 += a4.y * vh0[h4 * 4 + 1]; v1 += a4.y * vh1[h4 * 4 + 1];
      v0 += a4.z * vh0[h4 * 4 + 2]; v1 += a4.z * vh1[h4 * 4 + 2];
      v0 += a4.w * vh0[h4 * 4 + 3]; v1 += a4.w * vh1[h4 * 4 + 3];
    }
    if (j == r) { v0 = 0.f; v1 = 0.f; }
    if (active) {
      const unsigned u = bf16_bits(v0) | (bf16_bits(v1) << 16);  // q1>=21 -> hi=0 exactly
      *(unsigned*)(dst + (size_t)(j * JJSTR + byte_off)) = u;
    }
  }
}

// async 16B global->LDS
#define GLOAD16(ldst, gsrc)                                                            \
  __builtin_amdgcn_global_load_lds((const __attribute__((address_space(1))) void*)(gsrc), \
                                   (__attribute__((address_space(3))) void*)(ldst), 16, 0, 0)

// ---------------- gather: E[q,r,m] from bf16 J rows, logsumexp, pl ----------------
// grid (r=256, mt=8), block 512; thread owns 2 consecutive m (1024 m per block -> same
// staging traffic and per-chunk work as the proven r7 layout). (512,6): 3 blocks/CU =
// 24 waves, VGPR cap ~85 (measured TM=2 live set = 44, r8). Occupancy probe for the
// LDS-issue-bound gather: wave-issue-limited -> big win; CU-pipe-saturated -> flat.
__global__ __launch_bounds__(GBLK, 6) void gather_kernel(const unsigned char* __restrict__ Jg,
                                                         const unsigned short* __restrict__ Zs,
                                                         const int* __restrict__ Z,
                                                         const float* __restrict__ W,
                                                         float* __restrict__ out) {
  __shared__ __align__(16) unsigned char buf[2][CHUNK_B];
  __shared__ float red[GBLK];
  const int r = blockIdx.x, tid = threadIdx.x;
  const int mb = blockIdx.y * (TM * GBLK) + tid * TM;
  const unsigned char* Jr = Jg + (size_t)r * (L_ * JJSTR);

  v2f E2[TM][11];
#pragma unroll
  for (int k = 0; k < TM; ++k)
#pragma unroll
    for (int w = 0; w < 11; ++w) E2[k][w] = (v2f){0.f, 0.f};

  // prologue: stage chunk 0 -> buf[0]  (512 threads, 552 granules)
  {
    const unsigned char* src = Jr;
    GLOAD16(&buf[0][tid * 16], src + tid * 16);
    if (tid < NGRAN - GBLK) GLOAD16(&buf[0][(tid + GBLK) * 16], src + (tid + GBLK) * 16);
  }

  for (int c = 0; c < NCH; ++c) {
    __syncthreads();  // drains vmcnt: chunk c resident; buf[(c+1)&1] free
    if (c + 1 < NCH) {
      const unsigned char* src = Jr + (size_t)(c + 1) * CHUNK_B;
      unsigned char* db = buf[(c + 1) & 1];
      GLOAD16(db + tid * 16, src + tid * 16);
      if (tid < NGRAN - GBLK) GLOAD16(db + (tid + GBLK) * 16, src + (tid + GBLK) * 16);
    }
    const unsigned char* pb = buf[c & 1];
    for (int jj = 0; jj < JCH; ++jj) {
      const int j = c * JCH + jj;
      const ushort2 za = *(const ushort2*)(Zs + j * M_ + mb);  // pre-scaled byte offsets
      const int aoff[TM] = {(int)za.x, (int)za.y};
#pragma unroll
      for (int k = 0; k < TM; ++k) {
        const unsigned char* row = pb + jj * JJSTR + aoff[k];
        uint2 p[6];  // 6 x ds_read2_b32 (words 0..11; word 11 = pad, discarded)
#pragma unroll
        for (int w = 0; w < 6; ++w) __builtin_memcpy(&p[w], row + 8 * w, 8);
#pragma unroll
        for (int w = 0; w < 5; ++w) {
          const uint ua = p[w].x, ub = p[w].y;
          v2f ta, tb;
          ta.x = __uint_as_float(ua << 16);
          ta.y = __uint_as_float(ua & 0xFFFF0000u);
          tb.x = __uint_as_float(ub << 16);
          tb.y = __uint_as_float(ub & 0xFFFF0000u);
          E2[k][2 * w] += ta;      // v_pk_add_f32
          E2[k][2 * w + 1] += tb;
        }
        // word 10 (p[5].x): stored hi half is 0 -> raw word as f32 is denormal ~0;
        // E2[k][10].y is never consumed. word 11 (p[5].y) discarded.
        const uint uc = p[5].x;
        v2f tc;
        tc.x = __uint_as_float(uc << 16);
        tc.y = __uint_as_float(uc);
        E2[k][10] += tc;
      }
    }
  }

  const int2 zr = *(const int2*)(Z + r * M_ + mb);
  const int zra[TM] = {zr.x, zr.y};
  const float2 w2 = *(const float2*)(W + mb);
  const float wa[TM] = {w2.x, w2.y};
  float contrib = 0.f;
#pragma unroll
  for (int k = 0; k < TM; ++k) {
    float ev[QAA];
#pragma unroll
    for (int w = 0; w < 10; ++w) { ev[2 * w] = E2[k][w].x; ev[2 * w + 1] = E2[k][w].y; }
    ev[20] = E2[k][10].x;
    float mx = ev[0];
#pragma unroll
    for (int q = 1; q < QAA; ++q) mx = fmaxf(mx, ev[q]);
    float s = 0.f;
#pragma unroll
    for (int q = 0; q < QAA; ++q) s += __expf(ev[q] - mx);
    const float lge = mx + __logf(s);
    float Ec = ev[0];
#pragma unroll
    for (int q = 1; q < QAA; ++q) Ec = (zra[k] == q) ? ev[q] : Ec;
    contrib += wa[k] * (Ec - lge);
  }
  red[tid] = contrib;
  __syncthreads();
  for (int t = GBLK / 2; t > 0; t >>= 1) {
    if (tid < t) red[tid] += red[tid + t];
    __syncthreads();
  }
  if (tid == 0) atomicAdd(out, -red[0]);
}

// ---------------- legacy main (fallback when ws too small for J_g) ----------------
__global__ __launch_bounds__(256) void main_kernel(const float* __restrict__ A,
                                                   const float* __restrict__ Vaa,
                                                   const int* __restrict__ Z,
                                                   const float* __restrict__ W,
                                                   float* __restrict__ out) {
  __shared__ float A_r[H_ * L_];
  __shared__ float J_s[JC * AQ_];
  __shared__ float red[256];

  const int r = blockIdx.x;
  const int tid = threadIdx.x;
  const int mbase = blockIdx.y * (TML * 256) + tid;

  for (int e = tid; e < H_ * L_; e += 256) {
    const int h = e >> 8, j = e & 255;
    A_r[e] = A[(h * L_ + r) * L_ + j];
  }
  const int aq0 = tid, aq1 = tid + 256;
  const bool has1 = (aq1 < AQ_);
  float vh0[H_], vh1[H_];
#pragma unroll
  for (int h = 0; h < H_; ++h) {
    vh0[h] = Vaa[h * AQ_ + aq0];
    vh1[h] = has1 ? Vaa[h * AQ_ + aq1] : 0.f;
  }
  __syncthreads();

  float E[TML][QAA];
#pragma unroll
  for (int k = 0; k < TML; ++k)
#pragma unroll
    for (int q = 0; q < QAA; ++q) E[k][q] = 0.f;

  for (int j0 = 0; j0 < L_; j0 += JC) {
#pragma unroll
    for (int jj = 0; jj < JC; ++jj) {
      const int j = j0 + jj;
      float v0 = 0.f, v1 = 0.f;
#pragma unroll
      for (int h = 0; h < H_; ++h) {
        const float a = A_r[h * L_ + j];
        v0 += a * vh0[h];
        v1 += a * vh1[h];
      }
      if (j == r) { v0 = 0.f; v1 = 0.f; }
      J_s[jj * AQ_ + aq0] = v0;
      if (has1) J_s[jj * AQ_ + aq1] = v1;
    }
    __syncthreads();
#pragma unroll
    for (int jj = 0; jj < JC; ++jj) {
      const int j = j0 + jj;
      int a[TML];
#pragma unroll
      for (int k = 0; k < TML; ++k) a[k] = Z[j * M_ + mbase + k * 256];
#pragma unroll
      for (int k = 0; k < TML; ++k) {
        const float* row = &J_s[jj * AQ_ + a[k] * QAA];
#pragma unroll
        for (int q = 0; q < QAA; ++q) E[k][q] += row[q];
      }
    }
    __syncthreads();
  }

  float contrib = 0.f;
#pragma unroll
  for (int k = 0; k < TML; ++k) {
    const int m = mbase + k * 256;
    float mx = -1e30f;
#pragma unroll
    for (int q = 0; q < QAA; ++q) mx = fmaxf(mx, E[k][q]);
    float s = 0.f;
#pragma unroll
    for (int q = 0; q < QAA; ++q) s += __expf(E[k][q] - mx);
    const float lge = mx + __logf(s);
    const int zr = Z[r * M_ + m];
    float Ec = 0.f;
#pragma unroll
    for (int q = 0; q < QAA; ++q) Ec = (q == zr) ? E[k][q] : Ec;
    contrib += W[m] * (Ec - lge);
  }
  red[tid] = contrib;
  __syncthreads();
  for (int t = 128; t > 0; t >>= 1) {
    if (tid < t) red[tid] += red[tid + t];
    __syncthreads();
  }
  if (tid == 0) atomicAdd(out, -red[0]);
}

extern "C" void kernel_launch(void* const* d_in, const int* in_sizes, int n_in,
                              void* d_out, int out_size, void* d_ws, size_t ws_size,
                              hipStream_t stream) {
  const float* reps = (const float*)d_in[0];
  const float* Q    = (const float*)d_in[1];
  const float* K    = (const float*)d_in[2];
  const float* Vm   = (const float*)d_in[3];
  const int*   Z    = (const int*)d_in[4];
  const float* W    = (const float*)d_in[5];
  float* out = (float*)d_out;

  float* P   = (float*)d_ws;            // H*L*L f32 (dead after sym -> reused for Zs)
  float* A   = P + H_ * L_ * L_;        // H*L*L f32
  float* Vaa = A + H_ * L_ * L_;        // H*441 f32
  unsigned short* Zs = (unsigned short*)P;  // aliases dead P: L*M u16 = 4 MB < 8 MB
  (void)in_sizes; (void)n_in; (void)out_size;

  const size_t base = (size_t)2 * H_ * L_ * L_ * 4 + (size_t)H_ * AQ_ * 4;
  const size_t jg_off = (base + 255) & ~(size_t)255;
  const size_t need = jg_off + (size_t)L_ * L_ * JJSTR;

  hipMemsetAsync(out, 0, sizeof(float), stream);
  softmax_kernel<<<dim3(L_, H_), 256, 0, stream>>>(Q, K, P);
  sym_kernel<<<dim3(8, 8, H_), dim3(32, 8), 0, stream>>>(P, A);
  vaa_kernel<<<H_, 256, 0, stream>>>(reps, Vm, Vaa);
  reg_kernel<<<H_ * H_, 256, 0, stream>>>(A, Vaa, out);

  if (ws_size >= need) {
    unsigned char* Jg = (unsigned char*)d_ws + jg_off;
    zscale_kernel<<<(L_ * M_) / 1024, 256, 0, stream>>>(Z, Zs);  // after sym: P is dead
    jbuild_kernel<<<L_, 256, 0, stream>>>(A, Vaa, Jg);
    gather_kernel<<<dim3(L_, M_ / (TM * GBLK)), GBLK, 0, stream>>>(Jg, Zs, Z, W, out);
  } else {
    main_kernel<<<dim3(L_, M_ / (TML * 256)), 256, 0, stream>>>(A, Vaa, Z, W, out);
  }
}

// Round 10
// 1984.620 us; speedup vs baseline: 1.4528x; 1.4528x over previous
//
#include <hip/hip_runtime.h>
#include <hip/hip_bf16.h>

typedef unsigned int uint;
typedef float v2f __attribute__((ext_vector_type(2)));

#define H_ 32
#define L_ 256
#define DK_ 32
#define DV_ 32
#define QAA 21
#define AQ_ 441      // 21*21
#define DREP 64
#define M_ 8192
#define LAMBDA_ 1e-3f

// fast-path J layout (fp8 e4m3): per (r,j) block JJSTR bytes; row a at a*JSTR.
// JSTR = 28 B (7 words, odd -> 21 distinct start banks; mixed 4/8B alignment forces
// ds_read2_b32, the form measured conflict-free in r3/r5/r7). Row = 21 fp8 + 7 pad.
#define JSTR 28
#define JJSTR 592               // 21*28=588, padded to 16B multiple
#define JCH 8                   // j's per staged chunk
#define CHUNK_B (JCH * JJSTR)   // 4736
#define NGRAN (CHUNK_B / 16)    // 296 16B granules
#define NCH (L_ / JCH)          // 32

#define TM 4
// legacy-path params
#define JC 8
#define TML 4

// ---------------- softmax rows: P[h,i,j] = softmax_j(Q[h,i]·K[h,j]/sqrt(32)) ----------------
__global__ __launch_bounds__(256) void softmax_kernel(const float* __restrict__ Q,
                                                      const float* __restrict__ K,
                                                      float* __restrict__ P) {
  const int i = blockIdx.x, h = blockIdx.y, j = threadIdx.x;
  __shared__ float qrow[DK_];
  __shared__ float red[256];
  if (j < DK_) qrow[j] = Q[(h * L_ + i) * DK_ + j];
  __syncthreads();
  const float* krow = &K[(h * L_ + j) * DK_];
  float s = 0.f;
#pragma unroll
  for (int d = 0; d < DK_; ++d) s += qrow[d] * krow[d];
  s *= 0.17677669529663687f;  // 1/sqrt(32)
  red[j] = s;
  __syncthreads();
  for (int t = 128; t > 0; t >>= 1) {
    if (j < t) red[j] = fmaxf(red[j], red[j + t]);
    __syncthreads();
  }
  const float mx = red[0];
  __syncthreads();
  const float e = __expf(s - mx);
  red[j] = e;
  __syncthreads();
  for (int t = 128; t > 0; t >>= 1) {
    if (j < t) red[j] += red[j + t];
    __syncthreads();
  }
  P[(h * L_ + i) * L_ + j] = e / red[0];
}

// ---------------- A = 0.5*(P + P^T), LDS-tiled transpose ----------------
__global__ __launch_bounds__(256) void sym_kernel(const float* __restrict__ P,
                                                  float* __restrict__ A) {
  __shared__ float t1[32][33], t2[32][33];
  const int h = blockIdx.z;
  const int i0 = blockIdx.x * 32, j0 = blockIdx.y * 32;
  const int tx = threadIdx.x, ty = threadIdx.y;  // block (32,8)
#pragma unroll
  for (int ry = 0; ry < 4; ++ry) {
    const int row = ty + ry * 8;
    t1[row][tx] = P[(h * L_ + i0 + row) * L_ + j0 + tx];
    t2[row][tx] = P[(h * L_ + j0 + row) * L_ + i0 + tx];
  }
  __syncthreads();
#pragma unroll
  for (int ry = 0; ry < 4; ++ry) {
    const int row = ty + ry * 8;
    A[(h * L_ + i0 + row) * L_ + j0 + tx] = 0.5f * (t1[row][tx] + t2[tx][row]);
  }
}

// ---------------- Zs[j,m] = Z[j,m] * JSTR (u16 byte offsets) ----------------
__global__ __launch_bounds__(256) void zscale_kernel(const int* __restrict__ Z,
                                                     unsigned short* __restrict__ Zs) {
  const int i = (blockIdx.x * 256 + threadIdx.x) * 4;
  const int4 z = *(const int4*)(Z + i);
  ushort4 o;
  o.x = (unsigned short)(z.x * JSTR);
  o.y = (unsigned short)(z.y * JSTR);
  o.z = (unsigned short)(z.z * JSTR);
  o.w = (unsigned short)(z.w * JSTR);
  *(ushort4*)(Zs + i) = o;
}

// ---------------- Vaa[h,q,a] = exp(-gamma*max(D2,0)), V1 = reps @ Vm[h] ----------------
__global__ __launch_bounds__(256) void vaa_kernel(const float* __restrict__ reps,
                                                  const float* __restrict__ Vm,
                                                  float* __restrict__ Vaa) {
  const int h = blockIdx.x;
  __shared__ float V1[QAA * DV_];
  __shared__ float sq[QAA];
  for (int e = threadIdx.x; e < QAA * DV_; e += 256) {
    const int q = e >> 5, v = e & 31;
    float acc = 0.f;
#pragma unroll
    for (int d = 0; d < DREP; ++d) acc += reps[q * DREP + d] * Vm[(h * DREP + d) * DV_ + v];
    V1[e] = acc;
  }
  __syncthreads();
  if (threadIdx.x < QAA) {
    float acc = 0.f;
#pragma unroll
    for (int v = 0; v < DV_; ++v) { const float x = V1[threadIdx.x * DV_ + v]; acc += x * x; }
    sq[threadIdx.x] = acc;
  }
  __syncthreads();
  const float gamma = 1.f / 21.f;
  for (int e = threadIdx.x; e < AQ_; e += 256) {
    const int qq = e / QAA, aa = e - qq * QAA;
    float dot = 0.f;
#pragma unroll
    for (int v = 0; v < DV_; ++v) dot += V1[qq * DV_ + v] * V1[aa * DV_ + v];
    const float d2 = sq[qq] + sq[aa] - 2.f * dot;
    Vaa[h * AQ_ + e] = __expf(-gamma * fmaxf(d2, 0.f));
  }
}

// ---------------- reg = LAMBDA * sum_{h,h'} S[h,h'] * G[h,h'] ----------------
__global__ __launch_bounds__(256) void reg_kernel(const float* __restrict__ A,
                                                  const float* __restrict__ Vaa,
                                                  float* __restrict__ out) {
  const int h1 = blockIdx.x >> 5, h2 = blockIdx.x & 31;
  const float* A1 = A + h1 * (L_ * L_);
  const float* A2 = A + h2 * (L_ * L_);
  float s = 0.f;
  for (int idx = threadIdx.x; idx < L_ * L_; idx += 256) s += A1[idx] * A2[idx];
  s -= A1[threadIdx.x * (L_ + 1)] * A2[threadIdx.x * (L_ + 1)];
  float g = 0.f;
  const float* V1 = Vaa + h1 * AQ_;
  const float* V2 = Vaa + h2 * AQ_;
  for (int e = threadIdx.x; e < AQ_; e += 256) g += V1[e] * V2[e];
  __shared__ float redS[256], redG[256];
  redS[threadIdx.x] = s; redG[threadIdx.x] = g;
  __syncthreads();
  for (int t = 128; t > 0; t >>= 1) {
    if (threadIdx.x < t) {
      redS[threadIdx.x] += redS[threadIdx.x + t];
      redG[threadIdx.x] += redG[threadIdx.x + t];
    }
    __syncthreads();
  }
  if (threadIdx.x == 0) atomicAdd(out, LAMBDA_ * redS[0] * redG[0]);
}

// ---------------- producer: J_g[r][j][a-row: 21 fp8 e4m3 q-values, stride 28B] --------------
// J[r,j,q,a] = sum_h A[h,r,j]*Vaa[h, a*21+q] >= 0 (softmax x RBF); diag j==r zeroed.
// HW pack: v_cvt_pk_fp8_f32 (gfx950 = OCP e4m3fn), matching the gather's HW unpack.
__global__ __launch_bounds__(256) void jbuild_kernel(const float* __restrict__ A,
                                                     const float* __restrict__ Vaa,
                                                     unsigned char* __restrict__ Jg) {
  __shared__ float AT[L_ * H_];  // [j][h], 32 KB
  const int r = blockIdx.x, tid = threadIdx.x;
#pragma unroll
  for (int i = 0; i < H_; ++i) AT[tid * H_ + i] = A[(i * L_ + r) * L_ + tid];

  const int s = tid;
  const bool active = (s < 231);  // 21 rows * 11 byte-pairs
  int a = 0, w = 0;
  if (active) { a = s / 11; w = s - a * 11; }
  const int q0 = 2 * w, q1 = q0 + 1;
  float vh0[H_], vh1[H_];
#pragma unroll
  for (int h = 0; h < H_; ++h) {
    vh0[h] = (active && q0 < QAA) ? Vaa[h * AQ_ + a * QAA + q0] : 0.f;
    vh1[h] = (active && q1 < QAA) ? Vaa[h * AQ_ + a * QAA + q1] : 0.f;
  }
  __syncthreads();

  unsigned char* dst = Jg + (size_t)r * (L_ * JJSTR);
  const int byte_off = a * JSTR + w * 2;
  for (int j = 0; j < L_; ++j) {
    float v0 = 0.f, v1 = 0.f;
    const float4* Ar4 = (const float4*)&AT[j * H_];
#pragma unroll
    for (int h4 = 0; h4 < H_ / 4; ++h4) {
      const float4 a4 = Ar4[h4];
      v0 += a4.x * vh0[h4 * 4 + 0]; v1 += a4.x * vh1[h4 * 4 + 0];
      v0 += a4.y * vh0[h4 * 4 + 1]; v1 += a4.y * vh1[h4 * 4 + 1];
      v0 += a4.z * vh0[h4 * 4 + 2]; v1 += a4.z * vh1[h4 * 4 + 2];
      v0 += a4.w * vh0[h4 * 4 + 3]; v1 += a4.w * vh1[h4 * 4 + 3];
    }
    if (j == r) { v0 = 0.f; v1 = 0.f; }
    if (active) {
      // pack (v0,v1) -> 2 fp8 bytes in bits [15:0]; q1>=21 -> v1=0 -> byte = 0x00
      const int pk = __builtin_amdgcn_cvt_pk_fp8_f32(v0, v1, 0, false);
      *(unsigned short*)(dst + (size_t)(j * JJSTR + byte_off)) = (unsigned short)(pk & 0xFFFF);
    }
  }
}

// async 16B global->LDS
#define GLOAD16(ldst, gsrc)                                                            \
  __builtin_amdgcn_global_load_lds((const __attribute__((address_space(1))) void*)(gsrc), \
                                   (__attribute__((address_space(3))) void*)(ldst), 16, 0, 0)

// ---------------- gather: E[q,r,m] from fp8 J rows, logsumexp, pl ----------------
// grid (r=256, mt=8), block 256, TM=4, (256,3) regime (proven: 84 VGPR, no spill).
// Per (j,k): 3 x 8-byte loads (ds_read2_b32, odd 7-word stride -> conflict-free),
// HW unpack v_cvt_pk_f32_fp8 (11x) + v_pk_add_f32 (11x). LDS dwords/row: 12 -> 6.
__global__ __launch_bounds__(256, 3) void gather_kernel(const unsigned char* __restrict__ Jg,
                                                        const unsigned short* __restrict__ Zs,
                                                        const int* __restrict__ Z,
                                                        const float* __restrict__ W,
                                                        float* __restrict__ out) {
  __shared__ __align__(16) unsigned char buf[2][CHUNK_B];
  __shared__ float red[256];
  const int r = blockIdx.x, tid = threadIdx.x;
  const int mb = blockIdx.y * (TM * 256) + tid * TM;
  const unsigned char* Jr = Jg + (size_t)r * (L_ * JJSTR);

  v2f E2[TM][11];
#pragma unroll
  for (int k = 0; k < TM; ++k)
#pragma unroll
    for (int w = 0; w < 11; ++w) E2[k][w] = (v2f){0.f, 0.f};

  // prologue: stage chunk 0 -> buf[0]  (296 granules, 256 threads)
  {
    const unsigned char* src = Jr;
    GLOAD16(&buf[0][tid * 16], src + tid * 16);
    if (tid < NGRAN - 256) GLOAD16(&buf[0][(tid + 256) * 16], src + (tid + 256) * 16);
  }

  for (int c = 0; c < NCH; ++c) {
    __syncthreads();  // drains vmcnt: chunk c resident; buf[(c+1)&1] free
    if (c + 1 < NCH) {
      const unsigned char* src = Jr + (size_t)(c + 1) * CHUNK_B;
      unsigned char* db = buf[(c + 1) & 1];
      GLOAD16(db + tid * 16, src + tid * 16);
      if (tid < NGRAN - 256) GLOAD16(db + (tid + 256) * 16, src + (tid + 256) * 16);
    }
    const unsigned char* pb = buf[c & 1];
    for (int jj = 0; jj < JCH; ++jj) {
      const int j = c * JCH + jj;
      const ushort4 za = *(const ushort4*)(Zs + j * M_ + mb);  // pre-scaled byte offsets
      const int aoff[TM] = {(int)za.x, (int)za.y, (int)za.z, (int)za.w};
#pragma unroll
      for (int k = 0; k < TM; ++k) {
        const unsigned char* row = pb + jj * JJSTR + aoff[k];
        uint2 p0, p1, p2;  // 3 x ds_read2_b32: bytes 0..23 (21 vals + 3 pad)
        __builtin_memcpy(&p0, row, 8);
        __builtin_memcpy(&p1, row + 8, 8);
        __builtin_memcpy(&p2, row + 16, 8);
        E2[k][0] += __builtin_amdgcn_cvt_pk_f32_fp8((int)p0.x, false);
        E2[k][1] += __builtin_amdgcn_cvt_pk_f32_fp8((int)p0.x, true);
        E2[k][2] += __builtin_amdgcn_cvt_pk_f32_fp8((int)p0.y, false);
        E2[k][3] += __builtin_amdgcn_cvt_pk_f32_fp8((int)p0.y, true);
        E2[k][4] += __builtin_amdgcn_cvt_pk_f32_fp8((int)p1.x, false);
        E2[k][5] += __builtin_amdgcn_cvt_pk_f32_fp8((int)p1.x, true);
        E2[k][6] += __builtin_amdgcn_cvt_pk_f32_fp8((int)p1.y, false);
        E2[k][7] += __builtin_amdgcn_cvt_pk_f32_fp8((int)p1.y, true);
        E2[k][8] += __builtin_amdgcn_cvt_pk_f32_fp8((int)p2.x, false);
        E2[k][9] += __builtin_amdgcn_cvt_pk_f32_fp8((int)p2.x, true);
        // bytes 20,21: (val20, 0x00 written by jbuild). bytes 22,23 = pad, never converted.
        E2[k][10] += __builtin_amdgcn_cvt_pk_f32_fp8((int)p2.y, false);
      }
    }
  }

  const int4 zr = *(const int4*)(Z + r * M_ + mb);
  const int zra[TM] = {zr.x, zr.y, zr.z, zr.w};
  const float4 w4 = *(const float4*)(W + mb);
  const float wa[TM] = {w4.x, w4.y, w4.z, w4.w};
  float contrib = 0.f;
#pragma unroll
  for (int k = 0; k < TM; ++k) {
    float ev[QAA];
#pragma unroll
    for (int w = 0; w < 10; ++w) { ev[2 * w] = E2[k][w].x; ev[2 * w + 1] = E2[k][w].y; }
    ev[20] = E2[k][10].x;
    float mx = ev[0];
#pragma unroll
    for (int q = 1; q < QAA; ++q) mx = fmaxf(mx, ev[q]);
    float s = 0.f;
#pragma unroll
    for (int q = 0; q < QAA; ++q) s += __expf(ev[q] - mx);
    const float lge = mx + __logf(s);
    float Ec = ev[0];
#pragma unroll
    for (int q = 1; q < QAA; ++q) Ec = (zra[k] == q) ? ev[q] : Ec;
    contrib += wa[k] * (Ec - lge);
  }
  red[tid] = contrib;
  __syncthreads();
  for (int t = 128; t > 0; t >>= 1) {
    if (tid < t) red[tid] += red[tid + t];
    __syncthreads();
  }
  if (tid == 0) atomicAdd(out, -red[0]);
}

// ---------------- legacy main (fallback when ws too small for J_g) ----------------
__global__ __launch_bounds__(256) void main_kernel(const float* __restrict__ A,
                                                   const float* __restrict__ Vaa,
                                                   const int* __restrict__ Z,
                                                   const float* __restrict__ W,
                                                   float* __restrict__ out) {
  __shared__ float A_r[H_ * L_];
  __shared__ float J_s[JC * AQ_];
  __shared__ float red[256];

  const int r = blockIdx.x;
  const int tid = threadIdx.x;
  const int mbase = blockIdx.y * (TML * 256) + tid;

  for (int e = tid; e < H_ * L_; e += 256) {
    const int h = e >> 8, j = e & 255;
    A_r[e] = A[(h * L_ + r) * L_ + j];
  }
  const int aq0 = tid, aq1 = tid + 256;
  const bool has1 = (aq1 < AQ_);
  float vh0[H_], vh1[H_];
#pragma unroll
  for (int h = 0; h < H_; ++h) {
    vh0[h] = Vaa[h * AQ_ + aq0];
    vh1[h] = has1 ? Vaa[h * AQ_ + aq1] : 0.f;
  }
  __syncthreads();

  float E[TML][QAA];
#pragma unroll
  for (int k = 0; k < TML; ++k)
#pragma unroll
    for (int q = 0; q < QAA; ++q) E[k][q] = 0.f;

  for (int j0 = 0; j0 < L_; j0 += JC) {
#pragma unroll
    for (int jj = 0; jj < JC; ++jj) {
      const int j = j0 + jj;
      float v0 = 0.f, v1 = 0.f;
#pragma unroll
      for (int h = 0; h < H_; ++h) {
        const float a = A_r[h * L_ + j];
        v0 += a * vh0[h];
        v1 += a * vh1[h];
      }
      if (j == r) { v0 = 0.f; v1 = 0.f; }
      J_s[jj * AQ_ + aq0] = v0;
      if (has1) J_s[jj * AQ_ + aq1] = v1;
    }
    __syncthreads();
#pragma unroll
    for (int jj = 0; jj < JC; ++jj) {
      const int j = j0 + jj;
      int a[TML];
#pragma unroll
      for (int k = 0; k < TML; ++k) a[k] = Z[j * M_ + mbase + k * 256];
#pragma unroll
      for (int k = 0; k < TML; ++k) {
        const float* row = &J_s[jj * AQ_ + a[k] * QAA];
#pragma unroll
        for (int q = 0; q < QAA; ++q) E[k][q] += row[q];
      }
    }
    __syncthreads();
  }

  float contrib = 0.f;
#pragma unroll
  for (int k = 0; k < TML; ++k) {
    const int m = mbase + k * 256;
    float mx = -1e30f;
#pragma unroll
    for (int q = 0; q < QAA; ++q) mx = fmaxf(mx, E[k][q]);
    float s = 0.f;
#pragma unroll
    for (int q = 0; q < QAA; ++q) s += __expf(E[k][q] - mx);
    const float lge = mx + __logf(s);
    const int zr = Z[r * M_ + m];
    float Ec = 0.f;
#pragma unroll
    for (int q = 0; q < QAA; ++q) Ec = (q == zr) ? E[k][q] : Ec;
    contrib += W[m] * (Ec - lge);
  }
  red[tid] = contrib;
  __syncthreads();
  for (int t = 128; t > 0; t >>= 1) {
    if (tid < t) red[tid] += red[tid + t];
    __syncthreads();
  }
  if (tid == 0) atomicAdd(out, -red[0]);
}

extern "C" void kernel_launch(void* const* d_in, const int* in_sizes, int n_in,
                              void* d_out, int out_size, void* d_ws, size_t ws_size,
                              hipStream_t stream) {
  const float* reps = (const float*)d_in[0];
  const float* Q    = (const float*)d_in[1];
  const float* K    = (const float*)d_in[2];
  const float* Vm   = (const float*)d_in[3];
  const int*   Z    = (const int*)d_in[4];
  const float* W    = (const float*)d_in[5];
  float* out = (float*)d_out;

  float* P   = (float*)d_ws;            // H*L*L f32 (dead after sym -> reused for Zs)
  float* A   = P + H_ * L_ * L_;        // H*L*L f32
  float* Vaa = A + H_ * L_ * L_;        // H*441 f32
  unsigned short* Zs = (unsigned short*)P;  // aliases dead P: L*M u16 = 4 MB < 8 MB
  (void)in_sizes; (void)n_in; (void)out_size;

  const size_t base = (size_t)2 * H_ * L_ * L_ * 4 + (size_t)H_ * AQ_ * 4;
  const size_t jg_off = (base + 255) & ~(size_t)255;
  const size_t need = jg_off + (size_t)L_ * L_ * JJSTR;  // ~55.6 MB

  hipMemsetAsync(out, 0, sizeof(float), stream);
  softmax_kernel<<<dim3(L_, H_), 256, 0, stream>>>(Q, K, P);
  sym_kernel<<<dim3(8, 8, H_), dim3(32, 8), 0, stream>>>(P, A);
  vaa_kernel<<<H_, 256, 0, stream>>>(reps, Vm, Vaa);
  reg_kernel<<<H_ * H_, 256, 0, stream>>>(A, Vaa, out);

  if (ws_size >= need) {
    unsigned char* Jg = (unsigned char*)d_ws + jg_off;
    zscale_kernel<<<(L_ * M_) / 1024, 256, 0, stream>>>(Z, Zs);  // after sym: P is dead
    jbuild_kernel<<<L_, 256, 0, stream>>>(A, Vaa, Jg);
    gather_kernel<<<dim3(L_, M_ / (TM * 256)), 256, 0, stream>>>(Jg, Zs, Z, W, out);
  } else {
    main_kernel<<<dim3(L_, M_ / (TML * 256)), 256, 0, stream>>>(A, Vaa, Z, W, out);
  }
}

// Round 11
// 822.799 us; speedup vs baseline: 3.5043x; 2.4120x over previous
//
#include <hip/hip_runtime.h>
#include <hip/hip_bf16.h>

typedef unsigned int uint;
typedef float v2f __attribute__((ext_vector_type(2)));

#define H_ 32
#define L_ 256
#define DK_ 32
#define DV_ 32
#define QAA 21
#define AQ_ 441      // 21*21
#define DREP 64
#define M_ 8192
#define LAMBDA_ 1e-3f

// fast-path J layout: per (r,j) block of JJSTR bytes; row a starts at a*JSTR.
// JSTR = 13 words (52 B): odd word stride -> 21 distinct start banks; b32 reads are
// the empirically conflict-free AND fastest pattern (r5: 680 us, conflicts == 0;
// read2/f32/fp8 variants all tied or regressed r4-r10).
#define JSTR 52
#define JJSTR 1104              // 21*52=1092, padded to 16B multiple
#define JCH 16                  // j's per staged chunk (8->16: halves barrier count)
#define CHUNK_B (JCH * JJSTR)   // 17664
#define NGRAN (CHUNK_B / 16)    // 1104 16B granules
#define NCH (L_ / JCH)          // 16

// legacy-path params
#define JC 8
#define TM 4

// ---------------- softmax rows: P[h,i,j] = softmax_j(Q[h,i]·K[h,j]/sqrt(32)) ----------------
__global__ __launch_bounds__(256) void softmax_kernel(const float* __restrict__ Q,
                                                      const float* __restrict__ K,
                                                      float* __restrict__ P) {
  const int i = blockIdx.x, h = blockIdx.y, j = threadIdx.x;
  __shared__ float qrow[DK_];
  __shared__ float red[256];
  if (j < DK_) qrow[j] = Q[(h * L_ + i) * DK_ + j];
  __syncthreads();
  const float* krow = &K[(h * L_ + j) * DK_];
  float s = 0.f;
#pragma unroll
  for (int d = 0; d < DK_; ++d) s += qrow[d] * krow[d];
  s *= 0.17677669529663687f;  // 1/sqrt(32)
  red[j] = s;
  __syncthreads();
  for (int t = 128; t > 0; t >>= 1) {
    if (j < t) red[j] = fmaxf(red[j], red[j + t]);
    __syncthreads();
  }
  const float mx = red[0];
  __syncthreads();
  const float e = __expf(s - mx);
  red[j] = e;
  __syncthreads();
  for (int t = 128; t > 0; t >>= 1) {
    if (j < t) red[j] += red[j + t];
    __syncthreads();
  }
  P[(h * L_ + i) * L_ + j] = e / red[0];
}

// ---------------- A = 0.5*(P + P^T), LDS-tiled transpose ----------------
__global__ __launch_bounds__(256) void sym_kernel(const float* __restrict__ P,
                                                  float* __restrict__ A) {
  __shared__ float t1[32][33], t2[32][33];
  const int h = blockIdx.z;
  const int i0 = blockIdx.x * 32, j0 = blockIdx.y * 32;
  const int tx = threadIdx.x, ty = threadIdx.y;  // block (32,8)
#pragma unroll
  for (int ry = 0; ry < 4; ++ry) {
    const int row = ty + ry * 8;
    t1[row][tx] = P[(h * L_ + i0 + row) * L_ + j0 + tx];
    t2[row][tx] = P[(h * L_ + j0 + row) * L_ + i0 + tx];
  }
  __syncthreads();
#pragma unroll
  for (int ry = 0; ry < 4; ++ry) {
    const int row = ty + ry * 8;
    A[(h * L_ + i0 + row) * L_ + j0 + tx] = 0.5f * (t1[row][tx] + t2[tx][row]);
  }
}

// ---------------- Vaa[h,q,a] = exp(-gamma*max(D2,0)), V1 = reps @ Vm[h] ----------------
__global__ __launch_bounds__(256) void vaa_kernel(const float* __restrict__ reps,
                                                  const float* __restrict__ Vm,
                                                  float* __restrict__ Vaa) {
  const int h = blockIdx.x;
  __shared__ float V1[QAA * DV_];
  __shared__ float sq[QAA];
  for (int e = threadIdx.x; e < QAA * DV_; e += 256) {
    const int q = e >> 5, v = e & 31;
    float acc = 0.f;
#pragma unroll
    for (int d = 0; d < DREP; ++d) acc += reps[q * DREP + d] * Vm[(h * DREP + d) * DV_ + v];
    V1[e] = acc;
  }
  __syncthreads();
  if (threadIdx.x < QAA) {
    float acc = 0.f;
#pragma unroll
    for (int v = 0; v < DV_; ++v) { const float x = V1[threadIdx.x * DV_ + v]; acc += x * x; }
    sq[threadIdx.x] = acc;
  }
  __syncthreads();
  const float gamma = 1.f / 21.f;
  for (int e = threadIdx.x; e < AQ_; e += 256) {
    const int qq = e / QAA, aa = e - qq * QAA;
    float dot = 0.f;
#pragma unroll
    for (int v = 0; v < DV_; ++v) dot += V1[qq * DV_ + v] * V1[aa * DV_ + v];
    const float d2 = sq[qq] + sq[aa] - 2.f * dot;
    Vaa[h * AQ_ + e] = __expf(-gamma * fmaxf(d2, 0.f));
  }
}

// ---------------- reg = LAMBDA * sum_{h,h'} S[h,h'] * G[h,h'] ----------------
__global__ __launch_bounds__(256) void reg_kernel(const float* __restrict__ A,
                                                  const float* __restrict__ Vaa,
                                                  float* __restrict__ out) {
  const int h1 = blockIdx.x >> 5, h2 = blockIdx.x & 31;
  const float* A1 = A + h1 * (L_ * L_);
  const float* A2 = A + h2 * (L_ * L_);
  float s = 0.f;
  for (int idx = threadIdx.x; idx < L_ * L_; idx += 256) s += A1[idx] * A2[idx];
  s -= A1[threadIdx.x * (L_ + 1)] * A2[threadIdx.x * (L_ + 1)];
  float g = 0.f;
  const float* V1 = Vaa + h1 * AQ_;
  const float* V2 = Vaa + h2 * AQ_;
  for (int e = threadIdx.x; e < AQ_; e += 256) g += V1[e] * V2[e];
  __shared__ float redS[256], redG[256];
  redS[threadIdx.x] = s; redG[threadIdx.x] = g;
  __syncthreads();
  for (int t = 128; t > 0; t >>= 1) {
    if (threadIdx.x < t) {
      redS[threadIdx.x] += redS[threadIdx.x + t];
      redG[threadIdx.x] += redG[threadIdx.x + t];
    }
    __syncthreads();
  }
  if (threadIdx.x == 0) atomicAdd(out, LAMBDA_ * redS[0] * redG[0]);
}

static __device__ inline unsigned bf16_bits(float x) {
  __hip_bfloat16 b = __float2bfloat16(x);
  unsigned short u;
  __builtin_memcpy(&u, &b, 2);
  return (unsigned)u;
}

// ---------------- producer: J_g[r][j][a-row: 21 bf16 q-values, stride 52B] ----------------
// J[r,j,q,a] = sum_h A[h,r,j]*Vaa[h, a*21+q]  (Vaa symmetric); diag j==r zeroed.
__global__ __launch_bounds__(256) void jbuild_kernel(const float* __restrict__ A,
                                                     const float* __restrict__ Vaa,
                                                     unsigned char* __restrict__ Jg) {
  __shared__ float AT[L_ * H_];  // [j][h], 32 KB
  const int r = blockIdx.x, tid = threadIdx.x;
#pragma unroll
  for (int i = 0; i < H_; ++i) AT[tid * H_ + i] = A[(i * L_ + r) * L_ + tid];

  const int s = tid;
  const bool active = (s < 231);  // 21 rows * 11 words
  int a = 0, w = 0;
  if (active) { a = s / 11; w = s - a * 11; }
  const int q0 = 2 * w, q1 = q0 + 1;
  float vh0[H_], vh1[H_];
#pragma unroll
  for (int h = 0; h < H_; ++h) {
    vh0[h] = (active && q0 < QAA) ? Vaa[h * AQ_ + a * QAA + q0] : 0.f;
    vh1[h] = (active && q1 < QAA) ? Vaa[h * AQ_ + a * QAA + q1] : 0.f;
  }
  __syncthreads();

  unsigned char* dst = Jg + (size_t)r * (L_ * JJSTR);
  const int byte_off = a * JSTR + w * 4;
  for (int j = 0; j < L_; ++j) {
    float v0 = 0.f, v1 = 0.f;
    const float4* Ar4 = (const float4*)&AT[j * H_];
#pragma unroll
    for (int h4 = 0; h4 < H_ / 4; ++h4) {
      const float4 a4 = Ar4[h4];
      v0 += a4.x * vh0[h4 * 4 + 0]; v1 += a4.x * vh1[h4 * 4 + 0];
      v0 += a4.y * vh0[h4 * 4 + 1]; v1 += a4.y * vh1[h4 * 4 + 1];
      v0 += a4.z * vh0[h4 * 4 + 2]; v1 += a4.z * vh1[h4 * 4 + 2];
      v0 += a4.w * vh0[h4 * 4 + 3]; v1 += a4.w * vh1[h4 * 4 + 3];
    }
    if (j == r) { v0 = 0.f; v1 = 0.f; }
    if (active) {
      const unsigned u = bf16_bits(v0) | (bf16_bits(v1) << 16);  // q1>=21 -> hi=0 exactly
      *(unsigned*)(dst + (size_t)(j * JJSTR + byte_off)) = u;
    }
  }
}

// async 16B global->LDS
#define GLOAD16(ldst, gsrc)                                                            \
  __builtin_amdgcn_global_load_lds((const __attribute__((address_space(1))) void*)(gsrc), \
                                   (__attribute__((address_space(3))) void*)(ldst), 16, 0, 0)

// ---------------- gather: E[q,r,m] from bf16 J rows, logsumexp, pl ----------------
// grid (r=256, mt=8), block 256; thread owns 4 consecutive m. E packed as <2 x float>.
// r5-proven structure: batch all TM*11 raw b32 words (static-indexed reg array) before
// unpack; (256,3) regime (84 VGPR, no spill). JCH=16 halves chunk/barrier count.
__global__ __launch_bounds__(256, 3) void gather_kernel(const unsigned char* __restrict__ Jg,
                                                        const int* __restrict__ Z,
                                                        const float* __restrict__ W,
                                                        float* __restrict__ out) {
  __shared__ __align__(16) unsigned char buf[2][CHUNK_B];
  __shared__ float red[256];
  const int r = blockIdx.x, tid = threadIdx.x;
  const int mb = blockIdx.y * 1024 + tid * 4;
  const unsigned char* Jr = Jg + (size_t)r * (L_ * JJSTR);

  v2f E2[TM][11];
#pragma unroll
  for (int k = 0; k < TM; ++k)
#pragma unroll
    for (int w = 0; w < 11; ++w) E2[k][w] = (v2f){0.f, 0.f};

  // prologue: stage chunk 0 -> buf[0]  (1104 granules, 256 threads: 4 full + tail 80)
  {
    const unsigned char* src = Jr;
    GLOAD16(&buf[0][tid * 16], src + tid * 16);
    GLOAD16(&buf[0][(tid + 256) * 16], src + (tid + 256) * 16);
    GLOAD16(&buf[0][(tid + 512) * 16], src + (tid + 512) * 16);
    GLOAD16(&buf[0][(tid + 768) * 16], src + (tid + 768) * 16);
    if (tid < NGRAN - 1024) GLOAD16(&buf[0][(tid + 1024) * 16], src + (tid + 1024) * 16);
  }

  for (int c = 0; c < NCH; ++c) {
    __syncthreads();  // drains vmcnt: chunk c resident; buf[(c+1)&1] free
    if (c + 1 < NCH) {
      const unsigned char* src = Jr + (size_t)(c + 1) * CHUNK_B;
      unsigned char* db = buf[(c + 1) & 1];
      GLOAD16(db + tid * 16, src + tid * 16);
      GLOAD16(db + (tid + 256) * 16, src + (tid + 256) * 16);
      GLOAD16(db + (tid + 512) * 16, src + (tid + 512) * 16);
      GLOAD16(db + (tid + 768) * 16, src + (tid + 768) * 16);
      if (tid < NGRAN - 1024) GLOAD16(db + (tid + 1024) * 16, src + (tid + 1024) * 16);
    }
    const unsigned char* pb = buf[c & 1];
    for (int jj = 0; jj < JCH; ++jj) {
      const int j = c * JCH + jj;
      const int4 za = *(const int4*)(Z + j * M_ + mb);
      const int aa[TM] = {za.x, za.y, za.z, za.w};
      uint u[TM][11];  // static-indexed (full unroll) -> registers; 44 reads in flight
#pragma unroll
      for (int k = 0; k < TM; ++k) {
        const uint* row = (const uint*)(pb + jj * JJSTR + aa[k] * JSTR);
#pragma unroll
        for (int w = 0; w < 11; ++w) u[k][w] = row[w];
      }
#pragma unroll
      for (int k = 0; k < TM; ++k) {
#pragma unroll
        for (int w = 0; w < 10; ++w) {
          v2f t;
          t.x = __uint_as_float(u[k][w] << 16);
          t.y = __uint_as_float(u[k][w] & 0xFFFF0000u);
          E2[k][w] += t;  // v_pk_add_f32
        }
        // w=10: stored hi half is 0, so raw word as f32 is a denormal (~0) -> skip the AND;
        // E2[k][10].y is never consumed in the epilogue anyway.
        v2f t;
        t.x = __uint_as_float(u[k][10] << 16);
        t.y = __uint_as_float(u[k][10]);
        E2[k][10] += t;
      }
    }
  }

  const int4 zr = *(const int4*)(Z + r * M_ + mb);
  const int zra[TM] = {zr.x, zr.y, zr.z, zr.w};
  const float4 w4 = *(const float4*)(W + mb);
  const float wa[TM] = {w4.x, w4.y, w4.z, w4.w};
  float contrib = 0.f;
#pragma unroll
  for (int k = 0; k < TM; ++k) {
    float ev[QAA];
#pragma unroll
    for (int w = 0; w < 10; ++w) { ev[2 * w] = E2[k][w].x; ev[2 * w + 1] = E2[k][w].y; }
    ev[20] = E2[k][10].x;
    float mx = ev[0];
#pragma unroll
    for (int q = 1; q < QAA; ++q) mx = fmaxf(mx, ev[q]);
    float s = 0.f;
#pragma unroll
    for (int q = 0; q < QAA; ++q) s += __expf(ev[q] - mx);
    const float lge = mx + __logf(s);
    float Ec = ev[0];
#pragma unroll
    for (int q = 1; q < QAA; ++q) Ec = (zra[k] == q) ? ev[q] : Ec;
    contrib += wa[k] * (Ec - lge);
  }
  red[tid] = contrib;
  __syncthreads();
  for (int t = 128; t > 0; t >>= 1) {
    if (tid < t) red[tid] += red[tid + t];
    __syncthreads();
  }
  if (tid == 0) atomicAdd(out, -red[0]);
}

// ---------------- legacy main (fallback when ws too small for J_g) ----------------
__global__ __launch_bounds__(256) void main_kernel(const float* __restrict__ A,
                                                   const float* __restrict__ Vaa,
                                                   const int* __restrict__ Z,
                                                   const float* __restrict__ W,
                                                   float* __restrict__ out) {
  __shared__ float A_r[H_ * L_];
  __shared__ float J_s[JC * AQ_];
  __shared__ float red[256];

  const int r = blockIdx.x;
  const int tid = threadIdx.x;
  const int mbase = blockIdx.y * (TM * 256) + tid;

  for (int e = tid; e < H_ * L_; e += 256) {
    const int h = e >> 8, j = e & 255;
    A_r[e] = A[(h * L_ + r) * L_ + j];
  }
  const int aq0 = tid, aq1 = tid + 256;
  const bool has1 = (aq1 < AQ_);
  float vh0[H_], vh1[H_];
#pragma unroll
  for (int h = 0; h < H_; ++h) {
    vh0[h] = Vaa[h * AQ_ + aq0];
    vh1[h] = has1 ? Vaa[h * AQ_ + aq1] : 0.f;
  }
  __syncthreads();

  float E[TM][QAA];
#pragma unroll
  for (int k = 0; k < TM; ++k)
#pragma unroll
    for (int q = 0; q < QAA; ++q) E[k][q] = 0.f;

  for (int j0 = 0; j0 < L_; j0 += JC) {
#pragma unroll
    for (int jj = 0; jj < JC; ++jj) {
      const int j = j0 + jj;
      float v0 = 0.f, v1 = 0.f;
#pragma unroll
      for (int h = 0; h < H_; ++h) {
        const float a = A_r[h * L_ + j];
        v0 += a * vh0[h];
        v1 += a * vh1[h];
      }
      if (j == r) { v0 = 0.f; v1 = 0.f; }
      J_s[jj * AQ_ + aq0] = v0;
      if (has1) J_s[jj * AQ_ + aq1] = v1;
    }
    __syncthreads();
#pragma unroll
    for (int jj = 0; jj < JC; ++jj) {
      const int j = j0 + jj;
      int a[TM];
#pragma unroll
      for (int k = 0; k < TM; ++k) a[k] = Z[j * M_ + mbase + k * 256];
#pragma unroll
      for (int k = 0; k < TM; ++k) {
        const float* row = &J_s[jj * AQ_ + a[k] * QAA];
#pragma unroll
        for (int q = 0; q < QAA; ++q) E[k][q] += row[q];
      }
    }
    __syncthreads();
  }

  float contrib = 0.f;
#pragma unroll
  for (int k = 0; k < TM; ++k) {
    const int m = mbase + k * 256;
    float mx = -1e30f;
#pragma unroll
    for (int q = 0; q < QAA; ++q) mx = fmaxf(mx, E[k][q]);
    float s = 0.f;
#pragma unroll
    for (int q = 0; q < QAA; ++q) s += __expf(E[k][q] - mx);
    const float lge = mx + __logf(s);
    const int zr = Z[r * M_ + m];
    float Ec = 0.f;
#pragma unroll
    for (int q = 0; q < QAA; ++q) Ec = (q == zr) ? E[k][q] : Ec;
    contrib += W[m] * (Ec - lge);
  }
  red[tid] = contrib;
  __syncthreads();
  for (int t = 128; t > 0; t >>= 1) {
    if (tid < t) red[tid] += red[tid + t];
    __syncthreads();
  }
  if (tid == 0) atomicAdd(out, -red[0]);
}

extern "C" void kernel_launch(void* const* d_in, const int* in_sizes, int n_in,
                              void* d_out, int out_size, void* d_ws, size_t ws_size,
                              hipStream_t stream) {
  const float* reps = (const float*)d_in[0];
  const float* Q    = (const float*)d_in[1];
  const float* K    = (const float*)d_in[2];
  const float* Vm   = (const float*)d_in[3];
  const int*   Z    = (const int*)d_in[4];
  const float* W    = (const float*)d_in[5];
  float* out = (float*)d_out;

  float* P   = (float*)d_ws;            // H*L*L f32
  float* A   = P + H_ * L_ * L_;        // H*L*L f32
  float* Vaa = A + H_ * L_ * L_;        // H*441 f32
  (void)in_sizes; (void)n_in; (void)out_size;

  const size_t base = (size_t)2 * H_ * L_ * L_ * 4 + (size_t)H_ * AQ_ * 4;
  const size_t jg_off = (base + 255) & ~(size_t)255;
  const size_t need = jg_off + (size_t)L_ * L_ * JJSTR;

  hipMemsetAsync(out, 0, sizeof(float), stream);
  softmax_kernel<<<dim3(L_, H_), 256, 0, stream>>>(Q, K, P);
  sym_kernel<<<dim3(8, 8, H_), dim3(32, 8), 0, stream>>>(P, A);
  vaa_kernel<<<H_, 256, 0, stream>>>(reps, Vm, Vaa);
  reg_kernel<<<H_ * H_, 256, 0, stream>>>(A, Vaa, out);

  if (ws_size >= need) {
    unsigned char* Jg = (unsigned char*)d_ws + jg_off;
    jbuild_kernel<<<L_, 256, 0, stream>>>(A, Vaa, Jg);
    gather_kernel<<<dim3(L_, M_ / 1024), 256, 0, stream>>>(Jg, Z, W, out);
  } else {
    main_kernel<<<dim3(L_, M_ / (TM * 256)), 256, 0, stream>>>(A, Vaa, Z, W, out);
  }
}